// Round 2
// baseline (330.031 us; speedup 1.0000x reference)
//
#include <hip/hip_runtime.h>
#include <cstddef>

// Problem constants
#define Bsz 2
#define Lr  2048
#define Dr  1024
#define Nr  16
#define M_ROWS (Bsz*Lr)          // 4096
#define NPAD   1152              // padded (W_dt | W_B | W_C | zeros), 9 tiles of 128
#define CHUNK  32
#define NCH    (Lr/CHUNK)        // 64

#define BM 128
#define BN 128
#define BK 32

typedef __attribute__((ext_vector_type(8))) __bf16 bf16x8;
typedef __attribute__((ext_vector_type(4))) float floatx4;

__device__ __forceinline__ unsigned short f2bf(float f) {
    unsigned u = __float_as_uint(f);
    u += 0x7fffu + ((u >> 16) & 1u);
    return (unsigned short)(u >> 16);
}

__device__ __forceinline__ float softplus_f(float x) {
    if (x > 0.f) return x + log1pf(__expf(-x));
    return log1pf(__expf(x));
}

__device__ __forceinline__ void gload_lds16(const unsigned short* g, unsigned short* l) {
    __builtin_amdgcn_global_load_lds((const __attribute__((address_space(1))) void*)g,
                                     (__attribute__((address_space(3))) void*)l, 16, 0, 0);
}

// ---------------- K0: LayerNorm -> xn (f32) + xn (bf16) ----------------
__global__ __launch_bounds__(256) void ln_kernel(const float* __restrict__ x,
                                                 const float* __restrict__ gamma,
                                                 const float* __restrict__ beta,
                                                 float* __restrict__ xn,
                                                 unsigned short* __restrict__ xnb) {
    int row = blockIdx.x;
    int tid = threadIdx.x;
    const float4* xr = (const float4*)(x + (size_t)row * Dr);
    float4 v = xr[tid];
    float s  = v.x + v.y + v.z + v.w;
    float ss = v.x*v.x + v.y*v.y + v.z*v.z + v.w*v.w;
    #pragma unroll
    for (int off = 32; off > 0; off >>= 1) {
        s  += __shfl_down(s, off);
        ss += __shfl_down(ss, off);
    }
    __shared__ float red[8];
    int wid = tid >> 6;
    if ((tid & 63) == 0) { red[wid*2] = s; red[wid*2+1] = ss; }
    __syncthreads();
    if (tid == 0) {
        float S = 0.f, SS = 0.f;
        #pragma unroll
        for (int w = 0; w < 4; w++) { S += red[w*2]; SS += red[w*2+1]; }
        float mu  = S * (1.f/Dr);
        float var = SS * (1.f/Dr) - mu*mu;
        red[0] = mu;
        red[1] = rsqrtf(var + 1e-5f);
    }
    __syncthreads();
    float mu = red[0], rs = red[1];
    const float4* gp = (const float4*)gamma;
    const float4* bp = (const float4*)beta;
    float4 g = gp[tid], bt = bp[tid];
    float4 o;
    o.x = (v.x - mu) * rs * g.x + bt.x;
    o.y = (v.y - mu) * rs * g.y + bt.y;
    o.z = (v.z - mu) * rs * g.z + bt.z;
    o.w = (v.w - mu) * rs * g.w + bt.w;
    ((float4*)(xn + (size_t)row * Dr))[tid] = o;
    ushort4 ob;
    ob.x = f2bf(o.x); ob.y = f2bf(o.y); ob.z = f2bf(o.z); ob.w = f2bf(o.w);
    ((ushort4*)(xnb + (size_t)row * Dr))[tid] = ob;
}

// ---------------- K1: pack weights (W_dt | W_B | W_C | 0) -> bf16 [NPAD x Dr] ----------------
__global__ __launch_bounds__(256) void pack_w_kernel(const float* __restrict__ Wdt,
                                                     const float* __restrict__ WB,
                                                     const float* __restrict__ WC,
                                                     unsigned short* __restrict__ Wcat) {
    int i = blockIdx.x * 256 + threadIdx.x;   // over NPAD*Dr = 1179648 (exact grid)
    int row = i >> 10;
    int col = i & 1023;
    float v;
    if (row < Dr)                 v = Wdt[i];
    else if (row < Dr + Nr)       v = WB[(row - Dr) * Dr + col];
    else if (row < Dr + 2*Nr)     v = WC[(row - Dr - Nr) * Dr + col];
    else                          v = 0.f;
    Wcat[i] = f2bf(v);
}

// ---------------- K2: MFMA GEMM (m97 pattern) [M_ROWS x NPAD] = xnb @ Wcat^T ----------------
// 128x128 tile, BK=32, 4 waves x (64x64 each: 4x4 of 16x16x32), global_load_lds width=16.
__global__ __launch_bounds__(256) void gemm_kernel(const unsigned short* __restrict__ xnb,
                                                   const unsigned short* __restrict__ w,
                                                   const float* __restrict__ b_dt,
                                                   float* __restrict__ dt,
                                                   float* __restrict__ bin,
                                                   float* __restrict__ cin) {
    __shared__ unsigned short As[BM * BK];  // 8 KB, row-major [128][32]
    __shared__ unsigned short Bs[BN * BK];  // 8 KB
    int tid  = threadIdx.x;
    int wave = tid >> 6;
    int lane = tid & 63;
    int lm   = lane & 15;
    int quad = lane >> 4;
    int mblk = blockIdx.x & 31;   // 32 M-tiles
    int nblk = blockIdx.x >> 5;   // 9 N-tiles
    int Mb = mblk * BM;
    int Nb = nblk * BN;
    int wm = (wave >> 1) * 64;
    int wn = (wave & 1)  * 64;

    floatx4 acc[4][4] = {};

    // staging: chunk c (16B) -> LDS byte offset c*16 == row (c/4), col element (c%4)*8
    int c0 = tid, c1 = tid + 256;
    const unsigned short* Ag0 = xnb + (size_t)(Mb + (c0 >> 2)) * Dr + ((c0 & 3) << 3);
    const unsigned short* Ag1 = xnb + (size_t)(Mb + (c1 >> 2)) * Dr + ((c1 & 3) << 3);
    const unsigned short* Bg0 = w   + (size_t)(Nb + (c0 >> 2)) * Dr + ((c0 & 3) << 3);
    const unsigned short* Bg1 = w   + (size_t)(Nb + (c1 >> 2)) * Dr + ((c1 & 3) << 3);
    unsigned short* Al0 = &As[c0 * 8];
    unsigned short* Al1 = &As[c1 * 8];
    unsigned short* Bl0 = &Bs[c0 * 8];
    unsigned short* Bl1 = &Bs[c1 * 8];

    const unsigned short* Ar = &As[(wm + lm) * BK + quad * 8];
    const unsigned short* Br = &Bs[(wn + lm) * BK + quad * 8];

    for (int kk = 0; kk < Dr; kk += BK) {
        gload_lds16(Ag0 + kk, Al0);
        gload_lds16(Ag1 + kk, Al1);
        gload_lds16(Bg0 + kk, Bl0);
        gload_lds16(Bg1 + kk, Bl1);
        __syncthreads();   // drains vmcnt -> LDS valid
        bf16x8 a[4], b[4];
        #pragma unroll
        for (int i = 0; i < 4; i++) {
            a[i] = *(const bf16x8*)(Ar + i * 16 * BK);
            b[i] = *(const bf16x8*)(Br + i * 16 * BK);
        }
        #pragma unroll
        for (int i = 0; i < 4; i++)
            #pragma unroll
            for (int j = 0; j < 4; j++)
                acc[i][j] = __builtin_amdgcn_mfma_f32_16x16x32_bf16(a[i], b[j], acc[i][j], 0, 0, 0);
        __syncthreads();   // before next-iter overwrite
    }

    // C/D layout: col = lane&15, row = (lane>>4)*4 + reg   [m89/m91]
    #pragma unroll
    for (int i = 0; i < 4; i++) {
        int grow0 = Mb + wm + i * 16 + quad * 4;
        #pragma unroll
        for (int j = 0; j < 4; j++) {
            int gcol = Nb + wn + j * 16 + lm;
            #pragma unroll
            for (int r = 0; r < 4; r++) {
                float v = acc[i][j][r];
                int row = grow0 + r;
                if (gcol < Dr) {
                    dt[(size_t)row * Dr + gcol] = softplus_f(v + b_dt[gcol]);
                } else if (gcol < Dr + Nr) {
                    bin[(size_t)row * Nr + (gcol - Dr)] = v;
                } else if (gcol < Dr + 2*Nr) {
                    cin[(size_t)row * Nr + (gcol - Dr - Nr)] = v;
                }
            }
        }
    }
}

// ---------------- K3: scan pass 1 (per-chunk local scan; emit P, h_end) ----------------
__global__ __launch_bounds__(256) void scan1_kernel(const float* __restrict__ dt,
                                                    const float* __restrict__ xn,
                                                    const float* __restrict__ bin,
                                                    const float* __restrict__ A_log,
                                                    float* __restrict__ Pws,
                                                    float* __restrict__ hendws) {
    int d  = blockIdx.x * 256 + threadIdx.x;
    int ch = blockIdx.y;
    int b  = blockIdx.z;
    int l0 = ch * CHUNK;
    size_t rowbase = (size_t)b * Lr + l0;

    float ac[16];
    #pragma unroll
    for (int i = 0; i < 4; i++) {
        float4 t = ((const float4*)(A_log + (size_t)d * Nr))[i];
        ac[i*4+0] = -__expf(t.x);
        ac[i*4+1] = -__expf(t.y);
        ac[i*4+2] = -__expf(t.z);
        ac[i*4+3] = -__expf(t.w);
    }

    __shared__ float lb[CHUNK * Nr];
    for (int i = threadIdx.x; i < CHUNK * Nr; i += 256)
        lb[i] = bin[rowbase * Nr + i];
    __syncthreads();

    float h[16];
    #pragma unroll
    for (int n = 0; n < 16; n++) h[n] = 0.f;
    float S = 0.f;

    const float* dtp = dt + rowbase * Dr + d;
    const float* xp  = xn + rowbase * Dr + d;

    for (int t = 0; t < CHUNK; t++) {
        float dtv = dtp[t * Dr];
        float xv  = xp[t * Dr];
        S += dtv;
        float cm = dtv * xv;
        const float* br = lb + t * Nr;
        float4 b0 = *(const float4*)(br);
        float4 b1 = *(const float4*)(br + 4);
        float4 b2 = *(const float4*)(br + 8);
        float4 b3 = *(const float4*)(br + 12);
        h[0]  = __expf(dtv*ac[0])  * h[0]  + cm * b0.x;
        h[1]  = __expf(dtv*ac[1])  * h[1]  + cm * b0.y;
        h[2]  = __expf(dtv*ac[2])  * h[2]  + cm * b0.z;
        h[3]  = __expf(dtv*ac[3])  * h[3]  + cm * b0.w;
        h[4]  = __expf(dtv*ac[4])  * h[4]  + cm * b1.x;
        h[5]  = __expf(dtv*ac[5])  * h[5]  + cm * b1.y;
        h[6]  = __expf(dtv*ac[6])  * h[6]  + cm * b1.z;
        h[7]  = __expf(dtv*ac[7])  * h[7]  + cm * b1.w;
        h[8]  = __expf(dtv*ac[8])  * h[8]  + cm * b2.x;
        h[9]  = __expf(dtv*ac[9])  * h[9]  + cm * b2.y;
        h[10] = __expf(dtv*ac[10]) * h[10] + cm * b2.z;
        h[11] = __expf(dtv*ac[11]) * h[11] + cm * b2.w;
        h[12] = __expf(dtv*ac[12]) * h[12] + cm * b3.x;
        h[13] = __expf(dtv*ac[13]) * h[13] + cm * b3.y;
        h[14] = __expf(dtv*ac[14]) * h[14] + cm * b3.z;
        h[15] = __expf(dtv*ac[15]) * h[15] + cm * b3.w;
    }

    size_t obase = (((size_t)(b * NCH + ch)) * Dr + d) * Nr;
    #pragma unroll
    for (int i = 0; i < 4; i++) {
        float4 p, he;
        p.x = __expf(S*ac[i*4+0]); p.y = __expf(S*ac[i*4+1]);
        p.z = __expf(S*ac[i*4+2]); p.w = __expf(S*ac[i*4+3]);
        he.x = h[i*4+0]; he.y = h[i*4+1]; he.z = h[i*4+2]; he.w = h[i*4+3];
        ((float4*)(Pws   + obase))[i] = p;
        ((float4*)(hendws + obase))[i] = he;
    }
}

// ---------------- K4: combine chunk states sequentially ----------------
__global__ __launch_bounds__(256) void combine_kernel(const float* __restrict__ Pws,
                                                      const float* __restrict__ hendws,
                                                      float* __restrict__ hinws) {
    int id = blockIdx.x * 256 + threadIdx.x;  // B*D*N = 32768
    int b  = id >> 14;
    int dn = id & 16383;
    size_t base = ((size_t)b * NCH) * (Dr * Nr) + dn;
    float hin = 0.f;
    for (int c = 0; c < NCH; c++) {
        size_t idx = base + (size_t)c * (Dr * Nr);
        hinws[idx] = hin;
        hin = Pws[idx] * hin + hendws[idx];
    }
}

// ---------------- K5: scan pass 2 (re-scan with h_in; emit y + D*residual) ----------------
__global__ __launch_bounds__(256) void scan2_kernel(const float* __restrict__ dt,
                                                    const float* __restrict__ xn,
                                                    const float* __restrict__ bin,
                                                    const float* __restrict__ cin,
                                                    const float* __restrict__ A_log,
                                                    const float* __restrict__ hinws,
                                                    const float* __restrict__ x,
                                                    const float* __restrict__ Dp,
                                                    float* __restrict__ out) {
    int d  = blockIdx.x * 256 + threadIdx.x;
    int ch = blockIdx.y;
    int b  = blockIdx.z;
    int l0 = ch * CHUNK;
    size_t rowbase = (size_t)b * Lr + l0;

    float ac[16];
    #pragma unroll
    for (int i = 0; i < 4; i++) {
        float4 t = ((const float4*)(A_log + (size_t)d * Nr))[i];
        ac[i*4+0] = -__expf(t.x);
        ac[i*4+1] = -__expf(t.y);
        ac[i*4+2] = -__expf(t.z);
        ac[i*4+3] = -__expf(t.w);
    }

    __shared__ float lb[CHUNK * Nr];
    __shared__ float lc[CHUNK * Nr];
    for (int i = threadIdx.x; i < CHUNK * Nr; i += 256) {
        lb[i] = bin[rowbase * Nr + i];
        lc[i] = cin[rowbase * Nr + i];
    }
    __syncthreads();

    size_t obase = (((size_t)(b * NCH + ch)) * Dr + d) * Nr;
    float h[16];
    #pragma unroll
    for (int i = 0; i < 4; i++) {
        float4 hv = ((const float4*)(hinws + obase))[i];
        h[i*4+0] = hv.x; h[i*4+1] = hv.y; h[i*4+2] = hv.z; h[i*4+3] = hv.w;
    }

    float dp = Dp[d];
    const float* dtp = dt + rowbase * Dr + d;
    const float* xp  = xn + rowbase * Dr + d;
    const float* xr  = x  + rowbase * Dr + d;
    float* op        = out + rowbase * Dr + d;

    for (int t = 0; t < CHUNK; t++) {
        float dtv = dtp[t * Dr];
        float xv  = xp[t * Dr];
        float cm = dtv * xv;
        const float* br = lb + t * Nr;
        const float* cr = lc + t * Nr;
        float4 b0 = *(const float4*)(br);
        float4 b1 = *(const float4*)(br + 4);
        float4 b2 = *(const float4*)(br + 8);
        float4 b3 = *(const float4*)(br + 12);
        float4 c0 = *(const float4*)(cr);
        float4 c1 = *(const float4*)(cr + 4);
        float4 c2 = *(const float4*)(cr + 8);
        float4 c3 = *(const float4*)(cr + 12);
        float y = 0.f;
        h[0]  = __expf(dtv*ac[0])  * h[0]  + cm * b0.x;  y += c0.x * h[0];
        h[1]  = __expf(dtv*ac[1])  * h[1]  + cm * b0.y;  y += c0.y * h[1];
        h[2]  = __expf(dtv*ac[2])  * h[2]  + cm * b0.z;  y += c0.z * h[2];
        h[3]  = __expf(dtv*ac[3])  * h[3]  + cm * b0.w;  y += c0.w * h[3];
        h[4]  = __expf(dtv*ac[4])  * h[4]  + cm * b1.x;  y += c1.x * h[4];
        h[5]  = __expf(dtv*ac[5])  * h[5]  + cm * b1.y;  y += c1.y * h[5];
        h[6]  = __expf(dtv*ac[6])  * h[6]  + cm * b1.z;  y += c1.z * h[6];
        h[7]  = __expf(dtv*ac[7])  * h[7]  + cm * b1.w;  y += c1.w * h[7];
        h[8]  = __expf(dtv*ac[8])  * h[8]  + cm * b2.x;  y += c2.x * h[8];
        h[9]  = __expf(dtv*ac[9])  * h[9]  + cm * b2.y;  y += c2.y * h[9];
        h[10] = __expf(dtv*ac[10]) * h[10] + cm * b2.z;  y += c2.z * h[10];
        h[11] = __expf(dtv*ac[11]) * h[11] + cm * b2.w;  y += c2.w * h[11];
        h[12] = __expf(dtv*ac[12]) * h[12] + cm * b3.x;  y += c3.x * h[12];
        h[13] = __expf(dtv*ac[13]) * h[13] + cm * b3.y;  y += c3.y * h[13];
        h[14] = __expf(dtv*ac[14]) * h[14] + cm * b3.z;  y += c3.z * h[14];
        h[15] = __expf(dtv*ac[15]) * h[15] + cm * b3.w;  y += c3.w * h[15];
        op[t * Dr] = y + dp * xr[t * Dr];
    }
}

// ---------------- host ----------------
extern "C" void kernel_launch(void* const* d_in, const int* in_sizes, int n_in,
                              void* d_out, int out_size, void* d_ws, size_t ws_size,
                              hipStream_t stream) {
    const float* x      = (const float*)d_in[0];
    const float* W_dt   = (const float*)d_in[1];
    const float* b_dt   = (const float*)d_in[2];
    const float* W_B    = (const float*)d_in[3];
    const float* W_C    = (const float*)d_in[4];
    const float* Dparam = (const float*)d_in[5];
    const float* A_log  = (const float*)d_in[6];
    const float* gamma  = (const float*)d_in[7];
    const float* beta   = (const float*)d_in[8];
    float* out = (float*)d_out;

    char* ws = (char*)d_ws;
    float*          xn   = (float*)(ws);                              // 16 MB
    unsigned short* xnb  = (unsigned short*)(ws + 16777216);          // 8 MB
    unsigned short* wcat = (unsigned short*)(ws + 25165824);          // 2.25 MB (NPAD x Dr)
    float*          dt   = (float*)(ws + 27525120);                   // 16 MB
    float*          bin  = (float*)(ws + 44302336);                   // 256 KB
    float*          cin  = (float*)(ws + 44564480);                   // 256 KB
    float*          Pws  = (float*)(ws + 44826624);                   // 8 MB
    float*          hend = (float*)(ws + 53215232);                   // 8 MB
    float*          hin  = (float*)(ws + 61603840);                   // 8 MB (total ~70.0 MB)

    ln_kernel<<<M_ROWS, 256, 0, stream>>>(x, gamma, beta, xn, xnb);
    pack_w_kernel<<<(NPAD * Dr) / 256, 256, 0, stream>>>(W_dt, W_B, W_C, wcat);
    gemm_kernel<<<(M_ROWS / BM) * (NPAD / BN), 256, 0, stream>>>(xnb, wcat, b_dt, dt, bin, cin);
    dim3 sgrid(Dr / 256, NCH, Bsz);
    scan1_kernel<<<sgrid, 256, 0, stream>>>(dt, xn, bin, A_log, Pws, hend);
    combine_kernel<<<(Bsz * Dr * Nr) / 256, 256, 0, stream>>>(Pws, hend, hin);
    scan2_kernel<<<sgrid, 256, 0, stream>>>(dt, xn, bin, cin, A_log, hin, x, Dparam, out);
}

// Round 3
// 191.060 us; speedup vs baseline: 1.7274x; 1.7274x over previous
//
#include <hip/hip_runtime.h>
#include <cstddef>

// Problem constants
#define Bsz 2
#define Lr  2048
#define Dr  1024
#define Nr  16
#define M_ROWS (Bsz*Lr)          // 4096
#define NPAD   1088              // padded (W_dt | W_B | W_C | zeros), 17 tiles of 64
#define CHUNK  32
#define NCH    (Lr/CHUNK)        // 64

#define BM 64
#define BN 64
#define BK 32

typedef __attribute__((ext_vector_type(8))) __bf16 bf16x8;
typedef __attribute__((ext_vector_type(4))) float floatx4;

__device__ __forceinline__ unsigned short f2bf(float f) {
    unsigned u = __float_as_uint(f);
    u += 0x7fffu + ((u >> 16) & 1u);
    return (unsigned short)(u >> 16);
}

__device__ __forceinline__ float softplus_f(float x) {
    if (x > 0.f) return x + log1pf(__expf(-x));
    return log1pf(__expf(x));
}

__device__ __forceinline__ void gload_lds16(const unsigned short* g, unsigned short* l) {
    __builtin_amdgcn_global_load_lds((const __attribute__((address_space(1))) void*)g,
                                     (__attribute__((address_space(3))) void*)l, 16, 0, 0);
}

// ---------------- K0: LayerNorm -> xn (f32) + xn (bf16) ----------------
__global__ __launch_bounds__(256) void ln_kernel(const float* __restrict__ x,
                                                 const float* __restrict__ gamma,
                                                 const float* __restrict__ beta,
                                                 float* __restrict__ xn,
                                                 unsigned short* __restrict__ xnb) {
    int row = blockIdx.x;
    int tid = threadIdx.x;
    const float4* xr = (const float4*)(x + (size_t)row * Dr);
    float4 v = xr[tid];
    float s  = v.x + v.y + v.z + v.w;
    float ss = v.x*v.x + v.y*v.y + v.z*v.z + v.w*v.w;
    #pragma unroll
    for (int off = 32; off > 0; off >>= 1) {
        s  += __shfl_down(s, off);
        ss += __shfl_down(ss, off);
    }
    __shared__ float red[8];
    int wid = tid >> 6;
    if ((tid & 63) == 0) { red[wid*2] = s; red[wid*2+1] = ss; }
    __syncthreads();
    if (tid == 0) {
        float S = 0.f, SS = 0.f;
        #pragma unroll
        for (int w = 0; w < 4; w++) { S += red[w*2]; SS += red[w*2+1]; }
        float mu  = S * (1.f/Dr);
        float var = SS * (1.f/Dr) - mu*mu;
        red[0] = mu;
        red[1] = rsqrtf(var + 1e-5f);
    }
    __syncthreads();
    float mu = red[0], rs = red[1];
    const float4* gp = (const float4*)gamma;
    const float4* bp = (const float4*)beta;
    float4 g = gp[tid], bt = bp[tid];
    float4 o;
    o.x = (v.x - mu) * rs * g.x + bt.x;
    o.y = (v.y - mu) * rs * g.y + bt.y;
    o.z = (v.z - mu) * rs * g.z + bt.z;
    o.w = (v.w - mu) * rs * g.w + bt.w;
    ((float4*)(xn + (size_t)row * Dr))[tid] = o;
    ushort4 ob;
    ob.x = f2bf(o.x); ob.y = f2bf(o.y); ob.z = f2bf(o.z); ob.w = f2bf(o.w);
    ((ushort4*)(xnb + (size_t)row * Dr))[tid] = ob;
}

// ---------------- K1: pack weights (W_dt | W_B | W_C | 0) -> bf16 [NPAD x Dr] ----------------
__global__ __launch_bounds__(256) void pack_w_kernel(const float* __restrict__ Wdt,
                                                     const float* __restrict__ WB,
                                                     const float* __restrict__ WC,
                                                     unsigned short* __restrict__ Wcat) {
    int i = blockIdx.x * 256 + threadIdx.x;   // over NPAD*Dr = 1114112 (exact grid)
    int row = i >> 10;
    int col = i & 1023;
    float v;
    if (row < Dr)                 v = Wdt[i];
    else if (row < Dr + Nr)       v = WB[(row - Dr) * Dr + col];
    else if (row < Dr + 2*Nr)     v = WC[(row - Dr - Nr) * Dr + col];
    else                          v = 0.f;
    Wcat[i] = f2bf(v);
}

// ---------------- K2: MFMA GEMM [M_ROWS x NPAD] = xnb @ Wcat^T ----------------
// 64x64 tile (4 waves x 32x32 each: 2x2 of 16x16x32), global_load_lds width=16.
// grid = 64*17 = 1088 blocks -> ~4.25 blocks/CU: cross-block overlap hides the
// per-iter vmcnt(0) barrier drain (the 128-tile version at 288 blocks had 1
// block/CU and serialized on it -> 233us, MfmaUtil 1.6%).
__global__ __launch_bounds__(256, 6) void gemm_kernel(const unsigned short* __restrict__ xnb,
                                                      const unsigned short* __restrict__ w,
                                                      const float* __restrict__ b_dt,
                                                      float* __restrict__ dt,
                                                      float* __restrict__ bin,
                                                      float* __restrict__ cin) {
    __shared__ unsigned short As[BM * BK];  // 4 KB, row-major [64][32]
    __shared__ unsigned short Bs[BN * BK];  // 4 KB
    int tid  = threadIdx.x;
    int wave = tid >> 6;
    int lane = tid & 63;
    int lm   = lane & 15;
    int quad = lane >> 4;
    int mblk = blockIdx.x & 63;   // 64 M-tiles; all blocks sharing an A-tile land on one XCD (64%8==0)
    int nblk = blockIdx.x >> 6;   // 17 N-tiles
    int Mb = mblk * BM;
    int Nb = nblk * BN;
    int wm = (wave >> 1) * 32;
    int wn = (wave & 1)  * 32;

    floatx4 acc[2][2] = {};

    // staging: thread t loads 16B -> LDS offset t*16 (row t/4, col (t%4)*8)
    const unsigned short* Ag = xnb + (size_t)(Mb + (tid >> 2)) * Dr + ((tid & 3) << 3);
    const unsigned short* Bg = w   + (size_t)(Nb + (tid >> 2)) * Dr + ((tid & 3) << 3);
    unsigned short* Al = &As[tid * 8];
    unsigned short* Bl = &Bs[tid * 8];

    const unsigned short* Ar = &As[(wm + lm) * BK + quad * 8];
    const unsigned short* Br = &Bs[(wn + lm) * BK + quad * 8];

    for (int kk = 0; kk < Dr; kk += BK) {
        gload_lds16(Ag + kk, Al);
        gload_lds16(Bg + kk, Bl);
        __syncthreads();   // drains vmcnt -> LDS valid
        bf16x8 a[2], b[2];
        #pragma unroll
        for (int i = 0; i < 2; i++) {
            a[i] = *(const bf16x8*)(Ar + i * 16 * BK);
            b[i] = *(const bf16x8*)(Br + i * 16 * BK);
        }
        #pragma unroll
        for (int i = 0; i < 2; i++)
            #pragma unroll
            for (int j = 0; j < 2; j++)
                acc[i][j] = __builtin_amdgcn_mfma_f32_16x16x32_bf16(a[i], b[j], acc[i][j], 0, 0, 0);
        __syncthreads();   // before next-iter overwrite
    }

    // C/D layout: col = lane&15, row = (lane>>4)*4 + reg   [m89/m91]
    #pragma unroll
    for (int i = 0; i < 2; i++) {
        int grow0 = Mb + wm + i * 16 + quad * 4;
        #pragma unroll
        for (int j = 0; j < 2; j++) {
            int gcol = Nb + wn + j * 16 + lm;
            #pragma unroll
            for (int r = 0; r < 4; r++) {
                float v = acc[i][j][r];
                int row = grow0 + r;
                if (gcol < Dr) {
                    dt[(size_t)row * Dr + gcol] = softplus_f(v + b_dt[gcol]);
                } else if (gcol < Dr + Nr) {
                    bin[(size_t)row * Nr + (gcol - Dr)] = v;
                } else if (gcol < Dr + 2*Nr) {
                    cin[(size_t)row * Nr + (gcol - Dr - Nr)] = v;
                }
            }
        }
    }
}

// ---------------- K3: scan pass 1 (per-chunk local scan; emit P, h_end) ----------------
__global__ __launch_bounds__(256) void scan1_kernel(const float* __restrict__ dt,
                                                    const float* __restrict__ xn,
                                                    const float* __restrict__ bin,
                                                    const float* __restrict__ A_log,
                                                    float* __restrict__ Pws,
                                                    float* __restrict__ hendws) {
    int d  = blockIdx.x * 256 + threadIdx.x;
    int ch = blockIdx.y;
    int b  = blockIdx.z;
    int l0 = ch * CHUNK;
    size_t rowbase = (size_t)b * Lr + l0;

    float ac[16];
    #pragma unroll
    for (int i = 0; i < 4; i++) {
        float4 t = ((const float4*)(A_log + (size_t)d * Nr))[i];
        ac[i*4+0] = -__expf(t.x);
        ac[i*4+1] = -__expf(t.y);
        ac[i*4+2] = -__expf(t.z);
        ac[i*4+3] = -__expf(t.w);
    }

    __shared__ float lb[CHUNK * Nr];
    for (int i = threadIdx.x; i < CHUNK * Nr; i += 256)
        lb[i] = bin[rowbase * Nr + i];
    __syncthreads();

    float h[16];
    #pragma unroll
    for (int n = 0; n < 16; n++) h[n] = 0.f;
    float S = 0.f;

    const float* dtp = dt + rowbase * Dr + d;
    const float* xp  = xn + rowbase * Dr + d;

    for (int t = 0; t < CHUNK; t++) {
        float dtv = dtp[t * Dr];
        float xv  = xp[t * Dr];
        S += dtv;
        float cm = dtv * xv;
        const float* br = lb + t * Nr;
        float4 b0 = *(const float4*)(br);
        float4 b1 = *(const float4*)(br + 4);
        float4 b2 = *(const float4*)(br + 8);
        float4 b3 = *(const float4*)(br + 12);
        h[0]  = __expf(dtv*ac[0])  * h[0]  + cm * b0.x;
        h[1]  = __expf(dtv*ac[1])  * h[1]  + cm * b0.y;
        h[2]  = __expf(dtv*ac[2])  * h[2]  + cm * b0.z;
        h[3]  = __expf(dtv*ac[3])  * h[3]  + cm * b0.w;
        h[4]  = __expf(dtv*ac[4])  * h[4]  + cm * b1.x;
        h[5]  = __expf(dtv*ac[5])  * h[5]  + cm * b1.y;
        h[6]  = __expf(dtv*ac[6])  * h[6]  + cm * b1.z;
        h[7]  = __expf(dtv*ac[7])  * h[7]  + cm * b1.w;
        h[8]  = __expf(dtv*ac[8])  * h[8]  + cm * b2.x;
        h[9]  = __expf(dtv*ac[9])  * h[9]  + cm * b2.y;
        h[10] = __expf(dtv*ac[10]) * h[10] + cm * b2.z;
        h[11] = __expf(dtv*ac[11]) * h[11] + cm * b2.w;
        h[12] = __expf(dtv*ac[12]) * h[12] + cm * b3.x;
        h[13] = __expf(dtv*ac[13]) * h[13] + cm * b3.y;
        h[14] = __expf(dtv*ac[14]) * h[14] + cm * b3.z;
        h[15] = __expf(dtv*ac[15]) * h[15] + cm * b3.w;
    }

    size_t obase = (((size_t)(b * NCH + ch)) * Dr + d) * Nr;
    #pragma unroll
    for (int i = 0; i < 4; i++) {
        float4 p, he;
        p.x = __expf(S*ac[i*4+0]); p.y = __expf(S*ac[i*4+1]);
        p.z = __expf(S*ac[i*4+2]); p.w = __expf(S*ac[i*4+3]);
        he.x = h[i*4+0]; he.y = h[i*4+1]; he.z = h[i*4+2]; he.w = h[i*4+3];
        ((float4*)(Pws   + obase))[i] = p;
        ((float4*)(hendws + obase))[i] = he;
    }
}

// ---------------- K4: combine chunk states sequentially ----------------
__global__ __launch_bounds__(256) void combine_kernel(const float* __restrict__ Pws,
                                                      const float* __restrict__ hendws,
                                                      float* __restrict__ hinws) {
    int id = blockIdx.x * 256 + threadIdx.x;  // B*D*N = 32768
    int b  = id >> 14;
    int dn = id & 16383;
    size_t base = ((size_t)b * NCH) * (Dr * Nr) + dn;
    float hin = 0.f;
    for (int c = 0; c < NCH; c++) {
        size_t idx = base + (size_t)c * (Dr * Nr);
        hinws[idx] = hin;
        hin = Pws[idx] * hin + hendws[idx];
    }
}

// ---------------- K5: scan pass 2 (re-scan with h_in; emit y + D*residual) ----------------
__global__ __launch_bounds__(256) void scan2_kernel(const float* __restrict__ dt,
                                                    const float* __restrict__ xn,
                                                    const float* __restrict__ bin,
                                                    const float* __restrict__ cin,
                                                    const float* __restrict__ A_log,
                                                    const float* __restrict__ hinws,
                                                    const float* __restrict__ x,
                                                    const float* __restrict__ Dp,
                                                    float* __restrict__ out) {
    int d  = blockIdx.x * 256 + threadIdx.x;
    int ch = blockIdx.y;
    int b  = blockIdx.z;
    int l0 = ch * CHUNK;
    size_t rowbase = (size_t)b * Lr + l0;

    float ac[16];
    #pragma unroll
    for (int i = 0; i < 4; i++) {
        float4 t = ((const float4*)(A_log + (size_t)d * Nr))[i];
        ac[i*4+0] = -__expf(t.x);
        ac[i*4+1] = -__expf(t.y);
        ac[i*4+2] = -__expf(t.z);
        ac[i*4+3] = -__expf(t.w);
    }

    __shared__ float lb[CHUNK * Nr];
    __shared__ float lc[CHUNK * Nr];
    for (int i = threadIdx.x; i < CHUNK * Nr; i += 256) {
        lb[i] = bin[rowbase * Nr + i];
        lc[i] = cin[rowbase * Nr + i];
    }
    __syncthreads();

    size_t obase = (((size_t)(b * NCH + ch)) * Dr + d) * Nr;
    float h[16];
    #pragma unroll
    for (int i = 0; i < 4; i++) {
        float4 hv = ((const float4*)(hinws + obase))[i];
        h[i*4+0] = hv.x; h[i*4+1] = hv.y; h[i*4+2] = hv.z; h[i*4+3] = hv.w;
    }

    float dp = Dp[d];
    const float* dtp = dt + rowbase * Dr + d;
    const float* xp  = xn + rowbase * Dr + d;
    const float* xr  = x  + rowbase * Dr + d;
    float* op        = out + rowbase * Dr + d;

    for (int t = 0; t < CHUNK; t++) {
        float dtv = dtp[t * Dr];
        float xv  = xp[t * Dr];
        float cm = dtv * xv;
        const float* br = lb + t * Nr;
        const float* cr = lc + t * Nr;
        float4 b0 = *(const float4*)(br);
        float4 b1 = *(const float4*)(br + 4);
        float4 b2 = *(const float4*)(br + 8);
        float4 b3 = *(const float4*)(br + 12);
        float4 c0 = *(const float4*)(cr);
        float4 c1 = *(const float4*)(cr + 4);
        float4 c2 = *(const float4*)(cr + 8);
        float4 c3 = *(const float4*)(cr + 12);
        float y = 0.f;
        h[0]  = __expf(dtv*ac[0])  * h[0]  + cm * b0.x;  y += c0.x * h[0];
        h[1]  = __expf(dtv*ac[1])  * h[1]  + cm * b0.y;  y += c0.y * h[1];
        h[2]  = __expf(dtv*ac[2])  * h[2]  + cm * b0.z;  y += c0.z * h[2];
        h[3]  = __expf(dtv*ac[3])  * h[3]  + cm * b0.w;  y += c0.w * h[3];
        h[4]  = __expf(dtv*ac[4])  * h[4]  + cm * b1.x;  y += c1.x * h[4];
        h[5]  = __expf(dtv*ac[5])  * h[5]  + cm * b1.y;  y += c1.y * h[5];
        h[6]  = __expf(dtv*ac[6])  * h[6]  + cm * b1.z;  y += c1.z * h[6];
        h[7]  = __expf(dtv*ac[7])  * h[7]  + cm * b1.w;  y += c1.w * h[7];
        h[8]  = __expf(dtv*ac[8])  * h[8]  + cm * b2.x;  y += c2.x * h[8];
        h[9]  = __expf(dtv*ac[9])  * h[9]  + cm * b2.y;  y += c2.y * h[9];
        h[10] = __expf(dtv*ac[10]) * h[10] + cm * b2.z;  y += c2.z * h[10];
        h[11] = __expf(dtv*ac[11]) * h[11] + cm * b2.w;  y += c2.w * h[11];
        h[12] = __expf(dtv*ac[12]) * h[12] + cm * b3.x;  y += c3.x * h[12];
        h[13] = __expf(dtv*ac[13]) * h[13] + cm * b3.y;  y += c3.y * h[13];
        h[14] = __expf(dtv*ac[14]) * h[14] + cm * b3.z;  y += c3.z * h[14];
        h[15] = __expf(dtv*ac[15]) * h[15] + cm * b3.w;  y += c3.w * h[15];
        op[t * Dr] = y + dp * xr[t * Dr];
    }
}

// ---------------- host ----------------
extern "C" void kernel_launch(void* const* d_in, const int* in_sizes, int n_in,
                              void* d_out, int out_size, void* d_ws, size_t ws_size,
                              hipStream_t stream) {
    const float* x      = (const float*)d_in[0];
    const float* W_dt   = (const float*)d_in[1];
    const float* b_dt   = (const float*)d_in[2];
    const float* W_B    = (const float*)d_in[3];
    const float* W_C    = (const float*)d_in[4];
    const float* Dparam = (const float*)d_in[5];
    const float* A_log  = (const float*)d_in[6];
    const float* gamma  = (const float*)d_in[7];
    const float* beta   = (const float*)d_in[8];
    float* out = (float*)d_out;

    char* ws = (char*)d_ws;
    float*          xn   = (float*)(ws);                              // 16 MB
    unsigned short* xnb  = (unsigned short*)(ws + 16777216);          // 8 MB
    unsigned short* wcat = (unsigned short*)(ws + 25165824);          // 2.125 MB (NPAD x Dr)
    float*          dt   = (float*)(ws + 27525120);                   // 16 MB
    float*          bin  = (float*)(ws + 44302336);                   // 256 KB
    float*          cin  = (float*)(ws + 44564480);                   // 256 KB
    float*          Pws  = (float*)(ws + 44826624);                   // 8 MB
    float*          hend = (float*)(ws + 53215232);                   // 8 MB
    float*          hin  = (float*)(ws + 61603840);                   // 8 MB (total ~70.0 MB)

    ln_kernel<<<M_ROWS, 256, 0, stream>>>(x, gamma, beta, xn, xnb);
    pack_w_kernel<<<(NPAD * Dr) / 256, 256, 0, stream>>>(W_dt, W_B, W_C, wcat);
    gemm_kernel<<<(M_ROWS / BM) * (NPAD / BN), 256, 0, stream>>>(xnb, wcat, b_dt, dt, bin, cin);
    dim3 sgrid(Dr / 256, NCH, Bsz);
    scan1_kernel<<<sgrid, 256, 0, stream>>>(dt, xn, bin, A_log, Pws, hend);
    combine_kernel<<<(Bsz * Dr * Nr) / 256, 256, 0, stream>>>(Pws, hend, hin);
    scan2_kernel<<<sgrid, 256, 0, stream>>>(dt, xn, bin, cin, A_log, hin, x, Dparam, out);
}

// Round 4
// 190.869 us; speedup vs baseline: 1.7291x; 1.0010x over previous
//
#include <hip/hip_runtime.h>
#include <cstddef>

// Problem constants
#define Bsz 2
#define Lr  2048
#define Dr  1024
#define Nr  16
#define M_ROWS (Bsz*Lr)          // 4096
#define NPAD   1088              // padded (W_dt | W_B | W_C | zeros), 17 tiles of 64
#define CHUNK  32
#define NCH    (Lr/CHUNK)        // 64

#define BM 64
#define BN 64
#define BK 32
#define NK (Dr/BK)               // 32 K-iterations
#define LDSW 40                  // padded LDS row stride (elems): 80 B = 20 banks -> 2-way (free)

typedef __attribute__((ext_vector_type(8))) __bf16 bf16x8;
typedef __attribute__((ext_vector_type(4))) float floatx4;

__device__ __forceinline__ unsigned short f2bf(float f) {
    unsigned u = __float_as_uint(f);
    u += 0x7fffu + ((u >> 16) & 1u);
    return (unsigned short)(u >> 16);
}

__device__ __forceinline__ float softplus_f(float x) {
    if (x > 0.f) return x + log1pf(__expf(-x));
    return log1pf(__expf(x));
}

// ---------------- K0: fused LayerNorm (blocks 0..4095) + weight-pack (rest) ----------------
__global__ __launch_bounds__(256) void ln_pack_kernel(const float* __restrict__ x,
                                                      const float* __restrict__ gamma,
                                                      const float* __restrict__ beta,
                                                      float* __restrict__ xn,
                                                      unsigned short* __restrict__ xnb,
                                                      const float* __restrict__ Wdt,
                                                      const float* __restrict__ WB,
                                                      const float* __restrict__ WC,
                                                      unsigned short* __restrict__ Wcat) {
    if (blockIdx.x >= M_ROWS) {
        // ---- pack (W_dt | W_B | W_C | 0) -> bf16 [NPAD x Dr] ----
        int i = (blockIdx.x - M_ROWS) * 256 + threadIdx.x;  // over NPAD*Dr
        int row = i >> 10;
        int col = i & 1023;
        float v;
        if (row < Dr)                 v = Wdt[i];
        else if (row < Dr + Nr)       v = WB[(row - Dr) * Dr + col];
        else if (row < Dr + 2*Nr)     v = WC[(row - Dr - Nr) * Dr + col];
        else                          v = 0.f;
        Wcat[i] = f2bf(v);
        return;
    }
    int row = blockIdx.x;
    int tid = threadIdx.x;
    const float4* xr = (const float4*)(x + (size_t)row * Dr);
    float4 v = xr[tid];
    float s  = v.x + v.y + v.z + v.w;
    float ss = v.x*v.x + v.y*v.y + v.z*v.z + v.w*v.w;
    #pragma unroll
    for (int off = 32; off > 0; off >>= 1) {
        s  += __shfl_down(s, off);
        ss += __shfl_down(ss, off);
    }
    __shared__ float red[8];
    int wid = tid >> 6;
    if ((tid & 63) == 0) { red[wid*2] = s; red[wid*2+1] = ss; }
    __syncthreads();
    if (tid == 0) {
        float S = 0.f, SS = 0.f;
        #pragma unroll
        for (int w = 0; w < 4; w++) { S += red[w*2]; SS += red[w*2+1]; }
        float mu  = S * (1.f/Dr);
        float var = SS * (1.f/Dr) - mu*mu;
        red[0] = mu;
        red[1] = rsqrtf(var + 1e-5f);
    }
    __syncthreads();
    float mu = red[0], rs = red[1];
    float4 g = ((const float4*)gamma)[tid], bt = ((const float4*)beta)[tid];
    float4 o;
    o.x = (v.x - mu) * rs * g.x + bt.x;
    o.y = (v.y - mu) * rs * g.y + bt.y;
    o.z = (v.z - mu) * rs * g.z + bt.z;
    o.w = (v.w - mu) * rs * g.w + bt.w;
    ((float4*)(xn + (size_t)row * Dr))[tid] = o;
    ushort4 ob;
    ob.x = f2bf(o.x); ob.y = f2bf(o.y); ob.z = f2bf(o.z); ob.w = f2bf(o.w);
    ((ushort4*)(xnb + (size_t)row * Dr))[tid] = ob;
}

// ---------------- K2: MFMA GEMM [M_ROWS x NPAD] = xnb @ Wcat^T ----------------
// Register-prefetch + double-buffered LDS pipeline: global loads for tile k+2
// issued at iter k, consumed via ds_write at iter k+1 -> the barrier waits on
// lgkm (fast LDS ops) only, never on a global-memory drain. Padded LDS rows
// (LDSW=40) kill the 8-way ds_read_b128 bank conflicts of the stride-32 layout.
__global__ __launch_bounds__(256, 4) void gemm_kernel(const unsigned short* __restrict__ xnb,
                                                      const unsigned short* __restrict__ w,
                                                      const float* __restrict__ b_dt,
                                                      float* __restrict__ dt,
                                                      float* __restrict__ bin,
                                                      float* __restrict__ cin) {
    __shared__ unsigned short As[2][BM * LDSW];  // 2 x 5 KB
    __shared__ unsigned short Bs[2][BN * LDSW];  // 2 x 5 KB
    int tid  = threadIdx.x;
    int wave = tid >> 6;
    int lane = tid & 63;
    int lm   = lane & 15;
    int quad = lane >> 4;
    int mblk = blockIdx.x & 63;   // 64 M-tiles
    int nblk = blockIdx.x >> 6;   // 17 N-tiles
    int Mb = mblk * BM;
    int Nb = nblk * BN;
    int wm = (wave >> 1) * 32;
    int wn = (wave & 1)  * 32;

    // staging coords: thread t handles row t/4, 8-elem chunk t%4 of the 32-col tile
    int srow = tid >> 2, schunk = tid & 3;
    const bf16x8* Ag = (const bf16x8*)(xnb + (size_t)(Mb + srow) * Dr + schunk * 8);
    const bf16x8* Bg = (const bf16x8*)(w   + (size_t)(Nb + srow) * Dr + schunk * 8);
    unsigned short* Aw[2] = { &As[0][srow * LDSW + schunk * 8], &As[1][srow * LDSW + schunk * 8] };
    unsigned short* Bw[2] = { &Bs[0][srow * LDSW + schunk * 8], &Bs[1][srow * LDSW + schunk * 8] };
    const unsigned short* Ar[2] = { &As[0][(wm + lm) * LDSW + quad * 8], &As[1][(wm + lm) * LDSW + quad * 8] };
    const unsigned short* Br[2] = { &Bs[0][(wn + lm) * LDSW + quad * 8], &Bs[1][(wn + lm) * LDSW + quad * 8] };

    floatx4 acc[2][2] = {};

    // prologue: tile0 -> LDS buf0; tile1 held in regs
    bf16x8 pa[2], pb[2];
    pa[0] = Ag[0]; pb[0] = Bg[0];      // tile 0
    pa[1] = Ag[4]; pb[1] = Bg[4];      // tile 1 (+32 elems = +4 x8-chunks)
    *(bf16x8*)Aw[0] = pa[0];
    *(bf16x8*)Bw[0] = pb[0];
    __syncthreads();

    #pragma unroll
    for (int kp = 0; kp < NK; kp++) {
        int cur = kp & 1;
        // fragments for tile kp from buf[cur]
        bf16x8 a0 = *(const bf16x8*)(Ar[cur]);
        bf16x8 a1 = *(const bf16x8*)(Ar[cur] + 16 * LDSW);
        bf16x8 b0 = *(const bf16x8*)(Br[cur]);
        bf16x8 b1 = *(const bf16x8*)(Br[cur] + 16 * LDSW);
        // stage tile kp+1 (regs, loaded 2 iters ago) into the other buffer
        *(bf16x8*)Aw[1 - cur] = pa[(kp + 1) & 1];
        *(bf16x8*)Bw[1 - cur] = pb[(kp + 1) & 1];
        // prefetch tile kp+2 into the just-freed reg set (OOB-safe: lands in ws, never consumed)
        pa[cur] = Ag[(kp + 2) * 4];
        pb[cur] = Bg[(kp + 2) * 4];
        acc[0][0] = __builtin_amdgcn_mfma_f32_16x16x32_bf16(a0, b0, acc[0][0], 0, 0, 0);
        acc[0][1] = __builtin_amdgcn_mfma_f32_16x16x32_bf16(a0, b1, acc[0][1], 0, 0, 0);
        acc[1][0] = __builtin_amdgcn_mfma_f32_16x16x32_bf16(a1, b0, acc[1][0], 0, 0, 0);
        acc[1][1] = __builtin_amdgcn_mfma_f32_16x16x32_bf16(a1, b1, acc[1][1], 0, 0, 0);
        __syncthreads();
    }

    // C/D layout: col = lane&15, row = (lane>>4)*4 + reg   [m89/m91]
    #pragma unroll
    for (int i = 0; i < 2; i++) {
        int grow0 = Mb + wm + i * 16 + quad * 4;
        #pragma unroll
        for (int j = 0; j < 2; j++) {
            int gcol = Nb + wn + j * 16 + lm;
            #pragma unroll
            for (int r = 0; r < 4; r++) {
                float v = acc[i][j][r];
                int row = grow0 + r;
                if (gcol < Dr) {
                    dt[(size_t)row * Dr + gcol] = softplus_f(v + b_dt[gcol]);
                } else if (gcol < Dr + Nr) {
                    bin[(size_t)row * Nr + (gcol - Dr)] = v;
                } else if (gcol < Dr + 2*Nr) {
                    cin[(size_t)row * Nr + (gcol - Dr - Nr)] = v;
                }
            }
        }
    }
}

// ---------------- K3: scan pass 1 (per-chunk local scan; emit P, h_end) ----------------
__global__ __launch_bounds__(256) void scan1_kernel(const float* __restrict__ dt,
                                                    const float* __restrict__ xn,
                                                    const float* __restrict__ bin,
                                                    const float* __restrict__ A_log,
                                                    float* __restrict__ Pws,
                                                    float* __restrict__ hendws) {
    int d  = blockIdx.x * 256 + threadIdx.x;
    int ch = blockIdx.y;
    int b  = blockIdx.z;
    int l0 = ch * CHUNK;
    size_t rowbase = (size_t)b * Lr + l0;

    float ac[16];
    #pragma unroll
    for (int i = 0; i < 4; i++) {
        float4 t = ((const float4*)(A_log + (size_t)d * Nr))[i];
        ac[i*4+0] = -__expf(t.x);
        ac[i*4+1] = -__expf(t.y);
        ac[i*4+2] = -__expf(t.z);
        ac[i*4+3] = -__expf(t.w);
    }

    __shared__ float lb[CHUNK * Nr];
    for (int i = threadIdx.x; i < CHUNK * Nr; i += 256)
        lb[i] = bin[rowbase * Nr + i];
    __syncthreads();

    float h[16];
    #pragma unroll
    for (int n = 0; n < 16; n++) h[n] = 0.f;
    float S = 0.f;

    const float* dtp = dt + rowbase * Dr + d;
    const float* xp  = xn + rowbase * Dr + d;

    for (int t = 0; t < CHUNK; t++) {
        float dtv = dtp[t * Dr];
        float xv  = xp[t * Dr];
        S += dtv;
        float cm = dtv * xv;
        const float* br = lb + t * Nr;
        float4 b0 = *(const float4*)(br);
        float4 b1 = *(const float4*)(br + 4);
        float4 b2 = *(const float4*)(br + 8);
        float4 b3 = *(const float4*)(br + 12);
        h[0]  = __expf(dtv*ac[0])  * h[0]  + cm * b0.x;
        h[1]  = __expf(dtv*ac[1])  * h[1]  + cm * b0.y;
        h[2]  = __expf(dtv*ac[2])  * h[2]  + cm * b0.z;
        h[3]  = __expf(dtv*ac[3])  * h[3]  + cm * b0.w;
        h[4]  = __expf(dtv*ac[4])  * h[4]  + cm * b1.x;
        h[5]  = __expf(dtv*ac[5])  * h[5]  + cm * b1.y;
        h[6]  = __expf(dtv*ac[6])  * h[6]  + cm * b1.z;
        h[7]  = __expf(dtv*ac[7])  * h[7]  + cm * b1.w;
        h[8]  = __expf(dtv*ac[8])  * h[8]  + cm * b2.x;
        h[9]  = __expf(dtv*ac[9])  * h[9]  + cm * b2.y;
        h[10] = __expf(dtv*ac[10]) * h[10] + cm * b2.z;
        h[11] = __expf(dtv*ac[11]) * h[11] + cm * b2.w;
        h[12] = __expf(dtv*ac[12]) * h[12] + cm * b3.x;
        h[13] = __expf(dtv*ac[13]) * h[13] + cm * b3.y;
        h[14] = __expf(dtv*ac[14]) * h[14] + cm * b3.z;
        h[15] = __expf(dtv*ac[15]) * h[15] + cm * b3.w;
    }

    size_t obase = (((size_t)(b * NCH + ch)) * Dr + d) * Nr;
    #pragma unroll
    for (int i = 0; i < 4; i++) {
        float4 p, he;
        p.x = __expf(S*ac[i*4+0]); p.y = __expf(S*ac[i*4+1]);
        p.z = __expf(S*ac[i*4+2]); p.w = __expf(S*ac[i*4+3]);
        he.x = h[i*4+0]; he.y = h[i*4+1]; he.z = h[i*4+2]; he.w = h[i*4+3];
        ((float4*)(Pws   + obase))[i] = p;
        ((float4*)(hendws + obase))[i] = he;
    }
}

// ---------------- K4: combine chunk states sequentially ----------------
__global__ __launch_bounds__(256) void combine_kernel(const float* __restrict__ Pws,
                                                      const float* __restrict__ hendws,
                                                      float* __restrict__ hinws) {
    int id = blockIdx.x * 256 + threadIdx.x;  // B*D*N = 32768
    int b  = id >> 14;
    int dn = id & 16383;
    size_t base = ((size_t)b * NCH) * (Dr * Nr) + dn;
    float hin = 0.f;
    for (int c = 0; c < NCH; c++) {
        size_t idx = base + (size_t)c * (Dr * Nr);
        hinws[idx] = hin;
        hin = Pws[idx] * hin + hendws[idx];
    }
}

// ---------------- K5: scan pass 2 (re-scan with h_in; emit y + D*residual) ----------------
__global__ __launch_bounds__(256) void scan2_kernel(const float* __restrict__ dt,
                                                    const float* __restrict__ xn,
                                                    const float* __restrict__ bin,
                                                    const float* __restrict__ cin,
                                                    const float* __restrict__ A_log,
                                                    const float* __restrict__ hinws,
                                                    const float* __restrict__ x,
                                                    const float* __restrict__ Dp,
                                                    float* __restrict__ out) {
    int d  = blockIdx.x * 256 + threadIdx.x;
    int ch = blockIdx.y;
    int b  = blockIdx.z;
    int l0 = ch * CHUNK;
    size_t rowbase = (size_t)b * Lr + l0;

    float ac[16];
    #pragma unroll
    for (int i = 0; i < 4; i++) {
        float4 t = ((const float4*)(A_log + (size_t)d * Nr))[i];
        ac[i*4+0] = -__expf(t.x);
        ac[i*4+1] = -__expf(t.y);
        ac[i*4+2] = -__expf(t.z);
        ac[i*4+3] = -__expf(t.w);
    }

    __shared__ float lb[CHUNK * Nr];
    __shared__ float lc[CHUNK * Nr];
    for (int i = threadIdx.x; i < CHUNK * Nr; i += 256) {
        lb[i] = bin[rowbase * Nr + i];
        lc[i] = cin[rowbase * Nr + i];
    }
    __syncthreads();

    size_t obase = (((size_t)(b * NCH + ch)) * Dr + d) * Nr;
    float h[16];
    #pragma unroll
    for (int i = 0; i < 4; i++) {
        float4 hv = ((const float4*)(hinws + obase))[i];
        h[i*4+0] = hv.x; h[i*4+1] = hv.y; h[i*4+2] = hv.z; h[i*4+3] = hv.w;
    }

    float dp = Dp[d];
    const float* dtp = dt + rowbase * Dr + d;
    const float* xp  = xn + rowbase * Dr + d;
    const float* xr  = x  + rowbase * Dr + d;
    float* op        = out + rowbase * Dr + d;

    for (int t = 0; t < CHUNK; t++) {
        float dtv = dtp[t * Dr];
        float xv  = xp[t * Dr];
        float cm = dtv * xv;
        const float* br = lb + t * Nr;
        const float* cr = lc + t * Nr;
        float4 b0 = *(const float4*)(br);
        float4 b1 = *(const float4*)(br + 4);
        float4 b2 = *(const float4*)(br + 8);
        float4 b3 = *(const float4*)(br + 12);
        float4 c0 = *(const float4*)(cr);
        float4 c1 = *(const float4*)(cr + 4);
        float4 c2 = *(const float4*)(cr + 8);
        float4 c3 = *(const float4*)(cr + 12);
        float y = 0.f;
        h[0]  = __expf(dtv*ac[0])  * h[0]  + cm * b0.x;  y += c0.x * h[0];
        h[1]  = __expf(dtv*ac[1])  * h[1]  + cm * b0.y;  y += c0.y * h[1];
        h[2]  = __expf(dtv*ac[2])  * h[2]  + cm * b0.z;  y += c0.z * h[2];
        h[3]  = __expf(dtv*ac[3])  * h[3]  + cm * b0.w;  y += c0.w * h[3];
        h[4]  = __expf(dtv*ac[4])  * h[4]  + cm * b1.x;  y += c1.x * h[4];
        h[5]  = __expf(dtv*ac[5])  * h[5]  + cm * b1.y;  y += c1.y * h[5];
        h[6]  = __expf(dtv*ac[6])  * h[6]  + cm * b1.z;  y += c1.z * h[6];
        h[7]  = __expf(dtv*ac[7])  * h[7]  + cm * b1.w;  y += c1.w * h[7];
        h[8]  = __expf(dtv*ac[8])  * h[8]  + cm * b2.x;  y += c2.x * h[8];
        h[9]  = __expf(dtv*ac[9])  * h[9]  + cm * b2.y;  y += c2.y * h[9];
        h[10] = __expf(dtv*ac[10]) * h[10] + cm * b2.z;  y += c2.z * h[10];
        h[11] = __expf(dtv*ac[11]) * h[11] + cm * b2.w;  y += c2.w * h[11];
        h[12] = __expf(dtv*ac[12]) * h[12] + cm * b3.x;  y += c3.x * h[12];
        h[13] = __expf(dtv*ac[13]) * h[13] + cm * b3.y;  y += c3.y * h[13];
        h[14] = __expf(dtv*ac[14]) * h[14] + cm * b3.z;  y += c3.z * h[14];
        h[15] = __expf(dtv*ac[15]) * h[15] + cm * b3.w;  y += c3.w * h[15];
        op[t * Dr] = y + dp * xr[t * Dr];
    }
}

// ---------------- host ----------------
extern "C" void kernel_launch(void* const* d_in, const int* in_sizes, int n_in,
                              void* d_out, int out_size, void* d_ws, size_t ws_size,
                              hipStream_t stream) {
    const float* x      = (const float*)d_in[0];
    const float* W_dt   = (const float*)d_in[1];
    const float* b_dt   = (const float*)d_in[2];
    const float* W_B    = (const float*)d_in[3];
    const float* W_C    = (const float*)d_in[4];
    const float* Dparam = (const float*)d_in[5];
    const float* A_log  = (const float*)d_in[6];
    const float* gamma  = (const float*)d_in[7];
    const float* beta   = (const float*)d_in[8];
    float* out = (float*)d_out;

    char* ws = (char*)d_ws;
    float*          xn   = (float*)(ws);                              // 16 MB
    unsigned short* xnb  = (unsigned short*)(ws + 16777216);          // 8 MB
    unsigned short* wcat = (unsigned short*)(ws + 25165824);          // 2.125 MB (NPAD x Dr)
    float*          dt   = (float*)(ws + 27525120);                   // 16 MB
    float*          bin  = (float*)(ws + 44302336);                   // 256 KB
    float*          cin  = (float*)(ws + 44564480);                   // 256 KB
    float*          Pws  = (float*)(ws + 44826624);                   // 8 MB
    float*          hend = (float*)(ws + 53215232);                   // 8 MB
    float*          hin  = (float*)(ws + 61603840);                   // 8 MB (total ~70.0 MB)

    ln_pack_kernel<<<M_ROWS + (NPAD * Dr) / 256, 256, 0, stream>>>(
        x, gamma, beta, xn, xnb, W_dt, W_B, W_C, wcat);
    gemm_kernel<<<(M_ROWS / BM) * (NPAD / BN), 256, 0, stream>>>(xnb, wcat, b_dt, dt, bin, cin);
    dim3 sgrid(Dr / 256, NCH, Bsz);
    scan1_kernel<<<sgrid, 256, 0, stream>>>(dt, xn, bin, A_log, Pws, hend);
    combine_kernel<<<(Bsz * Dr * Nr) / 256, 256, 0, stream>>>(Pws, hend, hin);
    scan2_kernel<<<sgrid, 256, 0, stream>>>(dt, xn, bin, cin, A_log, hin, x, Dparam, out);
}